// Round 7
// baseline (601.173 us; speedup 1.0000x reference)
//
#include <hip/hip_runtime.h>

#define BT 16384
#define DK 4096
#define NE 64
#define BM 64                 // rows per block (= rows per wave tile)
#define NW 8                  // waves per block, split-K by 8
#define KW (DK / NW)          // 512 k per wave
#define KC 16                 // k floats per step (4 quads)
#define NS (KW / KC)          // 32 steps
#define NPROBS (BT * NE)
#define NIDX (NPROBS)
#define NWTS (NPROBS + BT * 2)

// One wave = full 64x64 (rows x experts) tile over its 512-k slice.
// lane: rlg=lane>>3 row-oct, elg=lane&7 expert-oct; 8x8 acc/lane.
// LDS per wave region (1024 f4): [buf 512][X 256 | W 256].
// SWIZZLE (bijective, both-sides): quad (r,q) stored at physical slot
//   p = (r>>1)*8 + (((r&1)*4+q) ^ (r>>3))
// -> read (t,i): bank-quad = ((i&1)*4+t)^rlg, distinct across all 8 rlg
//    => conflict-free b128 reads (verified R6: conflicts 5.5e7 -> 4.4e6).
// No barriers in main loop (wave-private regions).
//
// R7 FIX: epilogue row loop MUST be unrolled — a rolled loop runtime-indexes
// acc[][] which forces the whole accumulator array to scratch for the entire
// kernel (rule #20). This was the R4-R6 spill source (WRITE_SIZE 1.5 GB).

__global__ __attribute__((amdgpu_flat_work_group_size(512, 512),
                          amdgpu_waves_per_eu(2, 2)))
void token_router(
    const float* __restrict__ x, const float* __restrict__ W,
    float* __restrict__ out)
{
    __shared__ float4 sh[NW * 1024];   // 128 KB

    const int tid  = threadIdx.x;
    const int wv   = tid >> 6;
    const int lane = tid & 63;
    const int rlg  = lane >> 3;
    const int elg  = lane & 7;
    const long rowbase = (long)blockIdx.x * BM;

    // ---- staging sources: thread stages physical slot j*64+lane; invert the
    // swizzle to find which (row r, quad q) lives there, fetch from there. ----
    const float* gx[4];
    const float* gw[4];
#pragma unroll
    for (int j = 0; j < 4; ++j) {
        const int g  = j * 8 + (lane >> 3);
        const int rh = g >> 2;
        const int o  = (lane & 7) ^ rh;
        const int r  = 2 * g + (o >> 2);
        const int q  = o & 3;
        gx[j] = x + (rowbase + r) * (long)DK + wv * KW + q * 4;
        gw[j] = W + (long)r * DK + wv * KW + q * 4;
    }

    float4* const reg = sh + wv * 1024;     // this wave's private region
    float4* const stx = reg + lane;         // + buf + j*64  (linear writes)
    float4* const stw = reg + 256 + lane;
    const float4* const xb = reg + rlg * 32;        // + buf + (i>>1)*8 + sx[..]
    const float4* const wb = reg + 256 + elg * 32;  // + buf + (j>>1)*8 + sw[..]
    int sx[8], sw[8];
#pragma unroll
    for (int s = 0; s < 8; ++s) { sx[s] = s ^ rlg; sw[s] = s ^ elg; }

    float acc[8][8];
#pragma unroll
    for (int i = 0; i < 8; ++i)
#pragma unroll
        for (int j = 0; j < 8; ++j) acc[i][j] = 0.f;

    // prologue: stage step 0 into buf 0
#pragma unroll
    for (int j = 0; j < 4; ++j) {
        stx[j * 64] = *(const float4*)(gx[j]);
        stw[j * 64] = *(const float4*)(gw[j]);
    }

#define STEP(c, BUF, NBUF) do {                                               \
    float4 pa[4], pb[4];                                                      \
    const bool pf = ((c) + 1 < NS);                                           \
    if (pf) {                                                                 \
        _Pragma("unroll") for (int j = 0; j < 4; ++j) {                       \
            pa[j] = *(const float4*)(gx[j] + ((c) + 1) * KC);                 \
            pb[j] = *(const float4*)(gw[j] + ((c) + 1) * KC);                 \
        }                                                                     \
    }                                                                         \
    _Pragma("unroll") for (int t = 0; t < 4; ++t) {                           \
        float4 xq[8], wq[8];                                                  \
        _Pragma("unroll") for (int i = 0; i < 8; ++i)                         \
            xq[i] = xb[(BUF) + (i >> 1) * 8 + sx[((i & 1) << 2) | t]];        \
        _Pragma("unroll") for (int j = 0; j < 8; ++j)                         \
            wq[j] = wb[(BUF) + (j >> 1) * 8 + sw[((j & 1) << 2) | t]];        \
        _Pragma("unroll") for (int i = 0; i < 8; ++i)                         \
            _Pragma("unroll") for (int j = 0; j < 8; ++j) {                   \
                acc[i][j] = fmaf(xq[i].x, wq[j].x, acc[i][j]);                \
                acc[i][j] = fmaf(xq[i].y, wq[j].y, acc[i][j]);                \
                acc[i][j] = fmaf(xq[i].z, wq[j].z, acc[i][j]);                \
                acc[i][j] = fmaf(xq[i].w, wq[j].w, acc[i][j]);                \
            }                                                                 \
    }                                                                         \
    if (pf) {                                                                 \
        _Pragma("unroll") for (int j = 0; j < 4; ++j) {                       \
            stx[(NBUF) + j * 64] = pa[j];                                     \
            stw[(NBUF) + j * 64] = pb[j];                                     \
        }                                                                     \
    }                                                                         \
} while (0)

    for (int c = 0; c < NS; c += 2) {
        STEP(c, 0, 512);
        STEP(c + 1, 512, 0);
    }
#undef STEP

    // ---- split-K tree reduction (fixed order -> deterministic fp32) ----
    auto dump = [&](float4* r) {
#pragma unroll
        for (int i = 0; i < 8; ++i) {
            r[(i * 2 + 0) * 64 + lane] = make_float4(acc[i][0], acc[i][1], acc[i][2], acc[i][3]);
            r[(i * 2 + 1) * 64 + lane] = make_float4(acc[i][4], acc[i][5], acc[i][6], acc[i][7]);
        }
    };
    auto addin = [&](const float4* r) {
#pragma unroll
        for (int i = 0; i < 8; ++i) {
            float4 a = r[(i * 2 + 0) * 64 + lane];
            float4 b = r[(i * 2 + 1) * 64 + lane];
            acc[i][0] += a.x; acc[i][1] += a.y; acc[i][2] += a.z; acc[i][3] += a.w;
            acc[i][4] += b.x; acc[i][5] += b.y; acc[i][6] += b.z; acc[i][7] += b.w;
        }
    };
    __syncthreads();
    if (wv >= 4) dump(sh + wv * 1024);
    __syncthreads();
    if (wv < 4) addin(sh + (wv + 4) * 1024);
    __syncthreads();
    if (wv == 2 || wv == 3) dump(sh + wv * 1024);
    __syncthreads();
    if (wv < 2) addin(sh + (wv + 2) * 1024);
    __syncthreads();
    if (wv == 1) dump(sh + 1024);
    __syncthreads();

    if (wv == 0) {
        addin(sh + 1024);
        // per-row epilogue; row's 64 experts live across the 8 elg lanes.
        // MUST be unrolled: rolled loop -> runtime i -> acc[][] to scratch.
#pragma unroll
        for (int i = 0; i < 8; ++i) {
            float l[8];
#pragma unroll
            for (int j = 0; j < 8; ++j) l[j] = acc[i][j];
            float m = l[0];
#pragma unroll
            for (int j = 1; j < 8; ++j) m = fmaxf(m, l[j]);
            m = fmaxf(m, __shfl_xor(m, 1));
            m = fmaxf(m, __shfl_xor(m, 2));
            m = fmaxf(m, __shfl_xor(m, 4));
            float s = 0.f;
#pragma unroll
            for (int j = 0; j < 8; ++j) s += __expf(l[j] - m);
            s += __shfl_xor(s, 1);
            s += __shfl_xor(s, 2);
            s += __shfl_xor(s, 4);
            const float inv = 1.f / s;
            float p[8];
#pragma unroll
            for (int j = 0; j < 8; ++j) p[j] = __expf(l[j] - m) * inv;

            // local top-2 (ascending idx + strict > == stable lower-index ties)
            float v1 = p[0], v2 = -1.f;
            int   i1 = elg * 8, i2 = elg * 8;
#pragma unroll
            for (int j = 1; j < 8; ++j) {
                const int idx = elg * 8 + j;
                if (p[j] > v1)      { v2 = v1; i2 = i1; v1 = p[j]; i1 = idx; }
                else if (p[j] > v2) { v2 = p[j]; i2 = idx; }
            }
            // butterfly merge across elg lanes, ties -> lower index
#pragma unroll
            for (int ms = 1; ms < 8; ms <<= 1) {
                float b1 = __shfl_xor(v1, ms);
                float b2 = __shfl_xor(v2, ms);
                int  bi1 = __shfl_xor(i1, ms);
                int  bi2 = __shfl_xor(i2, ms);
                float n1, n2; int ni1, ni2;
                const bool btop = (b1 > v1) || (b1 == v1 && bi1 < i1);
                if (btop) {
                    n1 = b1; ni1 = bi1;
                    const bool asec = (v1 > b2) || (v1 == b2 && i1 < bi2);
                    n2 = asec ? v1 : b2; ni2 = asec ? i1 : bi2;
                } else {
                    n1 = v1; ni1 = i1;
                    const bool bsec = (b1 > v2) || (b1 == v2 && bi1 < i2);
                    n2 = bsec ? b1 : v2; ni2 = bsec ? bi1 : i2;
                }
                v1 = n1; i1 = ni1; v2 = n2; i2 = ni2;
            }

            const long grow = rowbase + rlg * 8 + i;
            *reinterpret_cast<float4*>(&out[grow * (long)NE + elg * 8]) =
                make_float4(p[0], p[1], p[2], p[3]);
            *reinterpret_cast<float4*>(&out[grow * (long)NE + elg * 8 + 4]) =
                make_float4(p[4], p[5], p[6], p[7]);
            if (elg == 0) {
                out[NIDX + grow * 2 + 0] = (float)i1;
                out[NIDX + grow * 2 + 1] = (float)i2;
                const float dn = v1 + v2 + 1e-9f;
                out[NWTS + grow * 2 + 0] = v1 / dn;
                out[NWTS + grow * 2 + 1] = v2 / dn;
            }
        }
    }
}

extern "C" void kernel_launch(void* const* d_in, const int* in_sizes, int n_in,
                              void* d_out, int out_size, void* d_ws, size_t ws_size,
                              hipStream_t stream) {
    const float* x = (const float*)d_in[0];
    const float* W = (const float*)d_in[1];
    float* out = (float*)d_out;
    dim3 grid(BT / BM);   // 256 blocks, 1 per CU
    dim3 block(512);      // 8 waves
    token_router<<<grid, block, 0, stream>>>(x, W, out);
}

// Round 8
// 511.262 us; speedup vs baseline: 1.1759x; 1.1759x over previous
//
#include <hip/hip_runtime.h>

#define BT 16384
#define DK 4096
#define NE 64
#define BM 32                 // rows per block
#define NW 8                  // waves per block = split-K factor
#define KW (DK / NW)          // 512 k per wave
#define KC 16                 // k floats per step (4 quads)
#define NS (KW / KC)          // 32 steps
#define NPROBS (BT * NE)
#define NIDX (NPROBS)
#define NWTS (NPROBS + BT * 2)

// Wave wv owns k-slice [wv*512, wv*512+512) of ALL 32 rows x 64 experts.
// lane = rlg*8+elg: per-lane tile 4 rows (ii*8+rlg) x 8 experts (elg*8+j).
//   acc[4][8] = 32 VGPRs  (fits the 128-VGPR pin with room to spare).
// X: staged in wave-private LDS, k-major [buf][t][row] -> ds_read_b128 with
//   bank-quad = rlg (8 distinct, 8-way elg broadcast) = conflict-free, no
//   swizzle. 2 f4 staged per lane per step; double-buffered; NO barriers in
//   the main loop.
// W: NOT in LDS -- direct VMEM loads. Per step the CU's W working set is
//   32 KB (L1-resident; W total 1 MB = L2-resident), each 16B chunk feeds
//   16 MACs. This halves DS instructions vs R6: DS 3456 cyc/CU/step vs
//   VALU 4096 cyc/SIMD/step -> VALU-bound at the 54.6us fp32-FMA floor.
// LDS 32.3 KB/block -> 2 blocks/CU = 4 waves/SIMD for latency hiding.

__global__ __launch_bounds__(512) void token_router(
    const float* __restrict__ x, const float* __restrict__ W,
    float* __restrict__ out)
{
    __shared__ float4 sh4[NW * 256];   // 32 KB: per wave [2 buf][4 t][32 rows]

    const int tid  = threadIdx.x;
    const int wv   = tid >> 6;         // k-slice id
    const int lane = tid & 63;
    const int rlg  = lane >> 3;        // 0..7
    const int elg  = lane & 7;         // 0..7
    const long rowbase = (long)blockIdx.x * BM;
    const int kq0 = wv * KW;

    // X staging: p=0 stages slot lane   = (t=lane>>5)*32 + (row=lane&31)
    //            p=1 stages slot lane+64 = (t=2+(lane>>5))*32 + row
    const int srow = lane & 31;
    const float* gx0 = x + (rowbase + srow) * (long)DK + kq0 + (lane >> 5) * 4;
    const float* gx1 = gx0 + 8;        // t+2 -> +8 floats

    float4* const reg = sh4 + wv * 256;          // wave-private region
    // W base for this lane's 8 experts (elg*8 .. elg*8+7), this wave's k-slice
    const float* wb = W + (long)(elg * 8) * DK + kq0;

    float acc[4][8];
#pragma unroll
    for (int ii = 0; ii < 4; ++ii)
#pragma unroll
        for (int j = 0; j < 8; ++j) acc[ii][j] = 0.f;

    // prologue: stage step 0 into buf 0
    reg[lane]      = *(const float4*)(gx0);
    reg[64 + lane] = *(const float4*)(gx1);

    for (int c = 0; c < NS; ++c) {
        const int buf = (c & 1) * 128;
        float4 px0, px1;
        if (c + 1 < NS) {                        // prefetch next X step (HBM)
            px0 = *(const float4*)(gx0 + (c + 1) * KC);
            px1 = *(const float4*)(gx1 + (c + 1) * KC);
        }
#pragma unroll
        for (int t = 0; t < 4; ++t) {
            float4 xq[4], wqv[8];
#pragma unroll
            for (int ii = 0; ii < 4; ++ii)
                xq[ii] = reg[buf + t * 32 + ii * 8 + rlg];
#pragma unroll
            for (int j = 0; j < 8; ++j)
                wqv[j] = *(const float4*)(wb + (long)j * DK + c * KC + t * 4);
#pragma unroll
            for (int ii = 0; ii < 4; ++ii)
#pragma unroll
                for (int j = 0; j < 8; ++j) {
                    acc[ii][j] = fmaf(xq[ii].x, wqv[j].x, acc[ii][j]);
                    acc[ii][j] = fmaf(xq[ii].y, wqv[j].y, acc[ii][j]);
                    acc[ii][j] = fmaf(xq[ii].z, wqv[j].z, acc[ii][j]);
                    acc[ii][j] = fmaf(xq[ii].w, wqv[j].w, acc[ii][j]);
                }
        }
        if (c + 1 < NS) {                        // write-late into other buffer
            const int nb = ((c + 1) & 1) * 128;
            reg[nb + lane]      = px0;
            reg[nb + 64 + lane] = px1;
        }
    }

    // ---- split-K tree reduction, scratch = the (now free) X buffers ----
    auto dump = [&](float4* r) {
#pragma unroll
        for (int ii = 0; ii < 4; ++ii) {
            r[(ii * 2 + 0) * 64 + lane] = make_float4(acc[ii][0], acc[ii][1], acc[ii][2], acc[ii][3]);
            r[(ii * 2 + 1) * 64 + lane] = make_float4(acc[ii][4], acc[ii][5], acc[ii][6], acc[ii][7]);
        }
    };
    auto addin = [&](const float4* r) {
#pragma unroll
        for (int ii = 0; ii < 4; ++ii) {
            float4 a = r[(ii * 2 + 0) * 64 + lane];
            float4 b = r[(ii * 2 + 1) * 64 + lane];
            acc[ii][0] += a.x; acc[ii][1] += a.y; acc[ii][2] += a.z; acc[ii][3] += a.w;
            acc[ii][4] += b.x; acc[ii][5] += b.y; acc[ii][6] += b.z; acc[ii][7] += b.w;
        }
    };
    __syncthreads();
    if (wv >= 4) dump(sh4 + (wv - 4) * 512);
    __syncthreads();
    if (wv < 4) addin(sh4 + wv * 512);
    __syncthreads();
    if (wv == 2 || wv == 3) dump(sh4 + (wv - 2) * 512);
    __syncthreads();
    if (wv < 2) addin(sh4 + wv * 512);
    __syncthreads();
    if (wv == 1) dump(sh4);
    __syncthreads();

    if (wv == 0) {
        addin(sh4);
        // per-row softmax + stable top-2; row's 64 experts across 8 elg lanes
#pragma unroll
        for (int ii = 0; ii < 4; ++ii) {
            float l[8];
#pragma unroll
            for (int j = 0; j < 8; ++j) l[j] = acc[ii][j];
            float m = l[0];
#pragma unroll
            for (int j = 1; j < 8; ++j) m = fmaxf(m, l[j]);
            m = fmaxf(m, __shfl_xor(m, 1));
            m = fmaxf(m, __shfl_xor(m, 2));
            m = fmaxf(m, __shfl_xor(m, 4));
            float s = 0.f;
#pragma unroll
            for (int j = 0; j < 8; ++j) s += __expf(l[j] - m);
            s += __shfl_xor(s, 1);
            s += __shfl_xor(s, 2);
            s += __shfl_xor(s, 4);
            const float inv = 1.f / s;
            float p[8];
#pragma unroll
            for (int j = 0; j < 8; ++j) p[j] = __expf(l[j] - m) * inv;

            // local top-2 (ascending idx + strict > == lower-index ties)
            float v1 = p[0], v2 = -1.f;
            int   i1 = elg * 8, i2 = elg * 8;
#pragma unroll
            for (int j = 1; j < 8; ++j) {
                const int idx = elg * 8 + j;
                if (p[j] > v1)      { v2 = v1; i2 = i1; v1 = p[j]; i1 = idx; }
                else if (p[j] > v2) { v2 = p[j]; i2 = idx; }
            }
            // butterfly merge across the 8 elg lanes, ties -> lower index
#pragma unroll
            for (int ms = 1; ms < 8; ms <<= 1) {
                float b1 = __shfl_xor(v1, ms);
                float b2 = __shfl_xor(v2, ms);
                int  bi1 = __shfl_xor(i1, ms);
                int  bi2 = __shfl_xor(i2, ms);
                float n1, n2; int ni1, ni2;
                const bool btop = (b1 > v1) || (b1 == v1 && bi1 < i1);
                if (btop) {
                    n1 = b1; ni1 = bi1;
                    const bool asec = (v1 > b2) || (v1 == b2 && i1 < bi2);
                    n2 = asec ? v1 : b2; ni2 = asec ? i1 : bi2;
                } else {
                    n1 = v1; ni1 = i1;
                    const bool bsec = (b1 > v2) || (b1 == v2 && bi1 < i2);
                    n2 = bsec ? b1 : v2; ni2 = bsec ? bi1 : i2;
                }
                v1 = n1; i1 = ni1; v2 = n2; i2 = ni2;
            }

            const long grow = rowbase + ii * 8 + rlg;   // matches X row map
            *reinterpret_cast<float4*>(&out[grow * (long)NE + elg * 8]) =
                make_float4(p[0], p[1], p[2], p[3]);
            *reinterpret_cast<float4*>(&out[grow * (long)NE + elg * 8 + 4]) =
                make_float4(p[4], p[5], p[6], p[7]);
            if (elg == 0) {
                out[NIDX + grow * 2 + 0] = (float)i1;
                out[NIDX + grow * 2 + 1] = (float)i2;
                const float dn = v1 + v2 + 1e-9f;
                out[NWTS + grow * 2 + 0] = v1 / dn;
                out[NWTS + grow * 2 + 1] = v2 / dn;
            }
        }
    }
}

extern "C" void kernel_launch(void* const* d_in, const int* in_sizes, int n_in,
                              void* d_out, int out_size, void* d_ws, size_t ws_size,
                              hipStream_t stream) {
    const float* x = (const float*)d_in[0];
    const float* W = (const float*)d_in[1];
    float* out = (float*)d_out;
    dim3 grid(BT / BM);   // 512 blocks -> 2 per CU
    dim3 block(512);      // 8 waves
    token_router<<<grid, block, 0, stream>>>(x, W, out);
}

// Round 9
// 186.351 us; speedup vs baseline: 3.2260x; 2.7435x over previous
//
#include <hip/hip_runtime.h>

#define BT 16384
#define DK 4096
#define NE 64
#define BM 32                 // rows per block
#define NW 8                  // waves per block = split-K factor
#define KW (DK / NW)          // 512 k per wave
#define KC 16                 // k floats per step
#define NS (KW / KC)          // 32 steps
#define NPROBS (BT * NE)
#define NIDX (NPROBS)
#define NWTS (NPROBS + BT * 2)

// compile-time float4 component select (folds; avoids &reg aliasing)
#define COMP(v, m) ((m) == 0 ? (v).x : (m) == 1 ? (v).y : (m) == 2 ? (v).z : (v).w)

// ---- pre-kernel: W (64 x 4096, row-major) -> W_T (4096 x 64, k-major) ----
__global__ __launch_bounds__(256) void wt_transpose(
    const float* __restrict__ W, float* __restrict__ WT)
{
    const int idx = blockIdx.x * 1024 + threadIdx.x * 4;  // 4 consecutive WT floats
    const int k = idx >> 6;
    const int e = idx & 63;
    float4 v;
    v.x = W[(long)(e + 0) * DK + k];
    v.y = W[(long)(e + 1) * DK + k];
    v.z = W[(long)(e + 2) * DK + k];
    v.w = W[(long)(e + 3) * DK + k];
    *reinterpret_cast<float4*>(WT + idx) = v;
}

// Wave wv owns k-slice [wv*512, +512) of all 32 rows x 64 experts.
// lane = rlg*8+elg: tile 4 rows (ii*8+rlg) x 8 experts (elg*8+j); acc[4][8].
// X: wave-private LDS, k-major [buf][t][row]; conflict-free (R8: 0 conflicts).
//    Prefetch distance 2 via hold regs -> ds_write never stalls on HBM, and
//    W vmcnt waits never include an outstanding HBM load.
// W: dense VMEM from W_T. Per step the wave streams a CONTIGUOUS 4KB block;
//    each b128 load covers 8 float4 inside one 256B k-row = 1-2 cache lines
//    (vs 8 scattered lines in R8 -> line-request/MSHR collapse).
__global__ __launch_bounds__(512) void token_router(
    const float* __restrict__ x, const float* __restrict__ WT,
    float* __restrict__ out)
{
    __shared__ float4 sh4[NW * 256];   // 32 KB: per wave [2 buf][4 t][32 rows]

    const int tid  = threadIdx.x;
    const int wv   = tid >> 6;
    const int lane = tid & 63;
    const int rlg  = lane >> 3;
    const int elg  = lane & 7;
    const long rowbase = (long)blockIdx.x * BM;
    const int kq0 = wv * KW;

    const int srow = lane & 31;
    const float* gx0 = x + (rowbase + srow) * (long)DK + kq0 + (lane >> 5) * 4;
    const float* gx1 = gx0 + 8;

    float4* const reg = sh4 + wv * 256;               // wave-private region
    const float* wtb = WT + (long)kq0 * 64 + elg * 8; // dense W_T base

    float acc[4][8];
#pragma unroll
    for (int ii = 0; ii < 4; ++ii)
#pragma unroll
        for (int j = 0; j < 8; ++j) acc[ii][j] = 0.f;

    // prologue: chunk 0 -> buf0; chunk 1 -> hold regs
    {
        float4 a0 = *(const float4*)(gx0);
        float4 a1 = *(const float4*)(gx1);
        reg[lane]      = a0;
        reg[64 + lane] = a1;
    }
    float4 h0 = *(const float4*)(gx0 + KC);
    float4 h1 = *(const float4*)(gx1 + KC);

    for (int c = 0; c < NS; ++c) {
        // write hold (chunk c+1) into the buffer freed at step c-1
        if (c + 1 < NS) {
            const int nb = ((c + 1) & 1) * 128;
            reg[nb + lane]      = h0;
            reg[nb + 64 + lane] = h1;
        }
        const int buf = (c & 1) * 128;
#pragma unroll
        for (int t = 0; t < 4; ++t) {
            float4 xq[4];
#pragma unroll
            for (int ii = 0; ii < 4; ++ii)
                xq[ii] = reg[buf + t * 32 + ii * 8 + rlg];
            float4 wq[4][2];   // [kk][expert-quad h]
#pragma unroll
            for (int kk = 0; kk < 4; ++kk)
#pragma unroll
                for (int h = 0; h < 2; ++h)
                    wq[kk][h] = *(const float4*)(wtb + (c * 16 + t * 4 + kk) * 64 + h * 4);
#pragma unroll
            for (int ii = 0; ii < 4; ++ii)
#pragma unroll
                for (int j = 0; j < 8; ++j) {
                    acc[ii][j] = fmaf(xq[ii].x, COMP(wq[0][j >> 2], j & 3), acc[ii][j]);
                    acc[ii][j] = fmaf(xq[ii].y, COMP(wq[1][j >> 2], j & 3), acc[ii][j]);
                    acc[ii][j] = fmaf(xq[ii].z, COMP(wq[2][j >> 2], j & 3), acc[ii][j]);
                    acc[ii][j] = fmaf(xq[ii].w, COMP(wq[3][j >> 2], j & 3), acc[ii][j]);
                }
        }
        if (c + 2 < NS) {      // refill hold with chunk c+2 (2-step distance)
            h0 = *(const float4*)(gx0 + (c + 2) * KC);
            h1 = *(const float4*)(gx1 + (c + 2) * KC);
        }
    }

    // ---- split-K tree reduction (fixed order -> deterministic fp32) ----
    auto dump = [&](float4* r) {
#pragma unroll
        for (int ii = 0; ii < 4; ++ii) {
            r[(ii * 2 + 0) * 64 + lane] = make_float4(acc[ii][0], acc[ii][1], acc[ii][2], acc[ii][3]);
            r[(ii * 2 + 1) * 64 + lane] = make_float4(acc[ii][4], acc[ii][5], acc[ii][6], acc[ii][7]);
        }
    };
    auto addin = [&](const float4* r) {
#pragma unroll
        for (int ii = 0; ii < 4; ++ii) {
            float4 a = r[(ii * 2 + 0) * 64 + lane];
            float4 b = r[(ii * 2 + 1) * 64 + lane];
            acc[ii][0] += a.x; acc[ii][1] += a.y; acc[ii][2] += a.z; acc[ii][3] += a.w;
            acc[ii][4] += b.x; acc[ii][5] += b.y; acc[ii][6] += b.z; acc[ii][7] += b.w;
        }
    };
    __syncthreads();
    if (wv >= 4) dump(sh4 + (wv - 4) * 512);
    __syncthreads();
    if (wv < 4) addin(sh4 + wv * 512);
    __syncthreads();
    if (wv == 2 || wv == 3) dump(sh4 + (wv - 2) * 512);
    __syncthreads();
    if (wv < 2) addin(sh4 + wv * 512);
    __syncthreads();
    if (wv == 1) dump(sh4);
    __syncthreads();

    if (wv == 0) {
        addin(sh4);
#pragma unroll
        for (int ii = 0; ii < 4; ++ii) {
            float l[8];
#pragma unroll
            for (int j = 0; j < 8; ++j) l[j] = acc[ii][j];
            float m = l[0];
#pragma unroll
            for (int j = 1; j < 8; ++j) m = fmaxf(m, l[j]);
            m = fmaxf(m, __shfl_xor(m, 1));
            m = fmaxf(m, __shfl_xor(m, 2));
            m = fmaxf(m, __shfl_xor(m, 4));
            float s = 0.f;
#pragma unroll
            for (int j = 0; j < 8; ++j) s += __expf(l[j] - m);
            s += __shfl_xor(s, 1);
            s += __shfl_xor(s, 2);
            s += __shfl_xor(s, 4);
            const float inv = 1.f / s;
            float p[8];
#pragma unroll
            for (int j = 0; j < 8; ++j) p[j] = __expf(l[j] - m) * inv;

            float v1 = p[0], v2 = -1.f;
            int   i1 = elg * 8, i2 = elg * 8;
#pragma unroll
            for (int j = 1; j < 8; ++j) {
                const int idx = elg * 8 + j;
                if (p[j] > v1)      { v2 = v1; i2 = i1; v1 = p[j]; i1 = idx; }
                else if (p[j] > v2) { v2 = p[j]; i2 = idx; }
            }
#pragma unroll
            for (int ms = 1; ms < 8; ms <<= 1) {
                float b1 = __shfl_xor(v1, ms);
                float b2 = __shfl_xor(v2, ms);
                int  bi1 = __shfl_xor(i1, ms);
                int  bi2 = __shfl_xor(i2, ms);
                float n1, n2; int ni1, ni2;
                const bool btop = (b1 > v1) || (b1 == v1 && bi1 < i1);
                if (btop) {
                    n1 = b1; ni1 = bi1;
                    const bool asec = (v1 > b2) || (v1 == b2 && i1 < bi2);
                    n2 = asec ? v1 : b2; ni2 = asec ? i1 : bi2;
                } else {
                    n1 = v1; ni1 = i1;
                    const bool bsec = (b1 > v2) || (b1 == v2 && bi1 < i2);
                    n2 = bsec ? b1 : v2; ni2 = bsec ? bi1 : i2;
                }
                v1 = n1; i1 = ni1; v2 = n2; i2 = ni2;
            }

            const long grow = rowbase + ii * 8 + rlg;
            *reinterpret_cast<float4*>(&out[grow * (long)NE + elg * 8]) =
                make_float4(p[0], p[1], p[2], p[3]);
            *reinterpret_cast<float4*>(&out[grow * (long)NE + elg * 8 + 4]) =
                make_float4(p[4], p[5], p[6], p[7]);
            if (elg == 0) {
                out[NIDX + grow * 2 + 0] = (float)i1;
                out[NIDX + grow * 2 + 1] = (float)i2;
                const float dn = v1 + v2 + 1e-9f;
                out[NWTS + grow * 2 + 0] = v1 / dn;
                out[NWTS + grow * 2 + 1] = v2 / dn;
            }
        }
    }
}

extern "C" void kernel_launch(void* const* d_in, const int* in_sizes, int n_in,
                              void* d_out, int out_size, void* d_ws, size_t ws_size,
                              hipStream_t stream) {
    const float* x = (const float*)d_in[0];
    const float* W = (const float*)d_in[1];
    float* out = (float*)d_out;
    float* WT  = (float*)d_ws;   // 4096*64*4 = 1 MB scratch

    wt_transpose<<<dim3(256), dim3(256), 0, stream>>>(W, WT);
    token_router<<<dim3(BT / BM), dim3(512), 0, stream>>>(x, WT, out);
}